// Round 5
// baseline (197.681 us; speedup 1.0000x reference)
//
#include <hip/hip_runtime.h>

// Problem constants
constexpr int Bc = 256;   // batch
constexpr int Nc = 512;   // nodes
constexpr int Dc = 256;   // dim_graph == dim_desc
constexpr int Rc = 64;    // rank

// ---- split-2 hot path (2 blocks per batch row -> 2 barrier domains/CU)
constexpr int SPLIT2 = 2;
constexpr int ROWS2  = Nc / SPLIT2;      // 256 rows per block
constexpr int NT1    = 512;              // 8 waves
constexpr int NTEAM1 = 32;               // 16-lane teams
constexpr int NSTEP1 = ROWS2 / NTEAM1;   // 8 row-steps per team

typedef float f4 __attribute__((ext_vector_type(4)));

// Workspace layout (floats) — ws is poisoned by the harness anyway, so free.
constexpr size_t WS_L = 0;                              // L_part[B][2]   : 512
constexpr size_t WS_H = WS_L + (size_t)Bc * SPLIT2;     // h_part[B][2][D]: 131072
constexpr size_t WS_FLOATS = WS_H + (size_t)Bc * SPLIT2 * Dc;

// ---------------------------------------------------------------- kernel 1
// grid (2, 256), 512 threads. Each block: 256 rows of one batch element.
//   1. q = tokns_k[b] @ Wq^T          (32 teams, 2 rows each) — redundant x2/b, cheap
//   2. p = q @ Wk                     (2 r-chunks across waves; p4 read straight
//                                      from the two partials — one barrier saved)
//      first 2 H-row loads are issued BEFORE phase 2 to hide HBM latency
//   3. stream 256 H rows: 16-lane teams, mask bitmap, 3-deep pipeline
//      (NT=512 -> 256-VGPR budget; the 3rd buffer is free here, unlike R4@1024)
//      masked rows: NO load, pn exactly 0 (validated R1-R4 semantics)
//   4. partial merge: raw pn -> out, h_part/L_part -> ws
__global__ __launch_bounds__(NT1) void k1_half(
    const float* __restrict__ tokns_k, const float* __restrict__ H_pad,
    const int* __restrict__ mask, const float* __restrict__ Wq,
    const float* __restrict__ Wk, const float* __restrict__ log_scale,
    float* __restrict__ ws, float* __restrict__ out)
{
    const int s = blockIdx.x;    // split 0..1
    const int b = blockIdx.y;    // batch
    const int t = threadIdx.x;
    const int wave = t >> 6, lane = t & 63, g = lane >> 4, l16 = lane & 15;
    const int team = wave * 4 + g;     // 0..31
    const int n0 = s * ROWS2;

    __shared__ float q_s[Rc];
    __shared__ __align__(16) float hm[NTEAM1][Dc];   // 32 KB team partials
    __shared__ __align__(16) float hq[2][Dc];        // 2 KB merge temp
    __shared__ float l_s[NTEAM1];
    __shared__ float pn_s[ROWS2];                    // exp(score), raw
    __shared__ int   mask_s[ROWS2];

    if (t < ROWS2) mask_s[t] = mask[b * Nc + n0 + t];

    const float inv_scale = 1.0f / fmaxf(__expf(log_scale[0]), 0.1f);

    // -------- phase 1: q[r] = tokns_k[b] . Wq[r]
    #pragma unroll
    for (int step = 0; step < 2; ++step) {
        const int r = step * NTEAM1 + team;
        float acc = 0.0f;
        #pragma unroll
        for (int j = 0; j < 4; ++j) {
            const float4 tk = *(const float4*)(tokns_k + b * Dc + l16 * 4 + j * 64);
            const float4 wq = *(const float4*)(Wq + r * Dc + l16 * 4 + j * 64);
            acc += tk.x * wq.x + tk.y * wq.y + tk.z * wq.z + tk.w * wq.w;
        }
        #pragma unroll
        for (int off = 1; off < 16; off <<= 1) acc += __shfl_xor(acc, off);
        if (l16 == 0) q_s[r] = acc;
    }
    __syncthreads();                    // q_s and mask_s ready

    // team mask bitmap (8 bits)
    int actbits = 0;
    #pragma unroll
    for (int k = 0; k < NSTEP1; ++k)
        actbits |= (mask_s[k * NTEAM1 + team] != 0) ? (1 << k) : 0;

    const float* __restrict__ Hb = H_pad + ((size_t)b * Nc + n0) * Dc;

    auto LOADROW = [&](f4 (&x)[4], int nr, bool act) {
        if (act) {
            const float* __restrict__ row = Hb + nr * Dc + l16 * 4;
            #pragma unroll
            for (int j = 0; j < 4; ++j)
                x[j] = __builtin_nontemporal_load((const f4*)(row + j * 64));
        }
    };

    // issue first two row-loads NOW — their latency hides under phase 2
    f4 xbuf[3][4];
    LOADROW(xbuf[0], 0 * NTEAM1 + team, (actbits >> 0) & 1);
    LOADROW(xbuf[1], 1 * NTEAM1 + team, (actbits >> 1) & 1);

    // -------- phase 2: p[d] = sum_r q[r] * Wk[r][d]  (2 r-chunks across waves)
    {
        const int rg = t >> 8;        // 0..1 (chunk of 32 r's)
        const int d  = t & 255;
        float acc = 0.0f;
        #pragma unroll
        for (int rr = 0; rr < 32; ++rr) {
            const int r = rg * 32 + rr;
            acc += q_s[r] * Wk[r * Dc + d];
        }
        hq[rg][d] = acc;
    }
    __syncthreads();

    // per-lane p fragment straight from the two partials (no p_s, no extra barrier)
    f4 p4[4];
    #pragma unroll
    for (int j = 0; j < 4; ++j)
        p4[j] = *(const f4*)(&hq[0][l16 * 4 + j * 64]) +
                *(const f4*)(&hq[1][l16 * 4 + j * 64]);

    // -------- phase 3: stream rows, 3-deep statically-indexed pipeline
    float l_acc = 0.0f;
    f4 h4[4];
    #pragma unroll
    for (int j = 0; j < 4; ++j) h4[j] = (f4){0.f, 0.f, 0.f, 0.f};

    auto PROCROW = [&](const f4 (&x)[4], int nr, bool act) {
        if (!act) {
            if (l16 == 0) pn_s[nr] = 0.0f;     // alpha exactly 0, no load done
            return;
        }
        float s0 = x[0][0] * p4[0][0] + x[0][1] * p4[0][1] + x[0][2] * p4[0][2] + x[0][3] * p4[0][3];
        float s1 = x[1][0] * p4[1][0] + x[1][1] * p4[1][1] + x[1][2] * p4[1][2] + x[1][3] * p4[1][3];
        float s2 = x[2][0] * p4[2][0] + x[2][1] * p4[2][1] + x[2][2] * p4[2][2] + x[2][3] * p4[2][3];
        float s3 = x[3][0] * p4[3][0] + x[3][1] * p4[3][1] + x[3][2] * p4[3][2] + x[3][3] * p4[3][3];
        float sc = (s0 + s1) + (s2 + s3);
        #pragma unroll
        for (int off = 1; off < 16; off <<= 1) sc += __shfl_xor(sc, off);
        sc *= inv_scale;

        const float pn = __expf(sc);           // |scores| << 88 (validated R2-R6)
        if (l16 == 0) pn_s[nr] = pn;
        l_acc += pn;
        #pragma unroll
        for (int j = 0; j < 4; ++j) {
            h4[j][0] = fmaf(pn, x[j][0], h4[j][0]);
            h4[j][1] = fmaf(pn, x[j][1], h4[j][1]);
            h4[j][2] = fmaf(pn, x[j][2], h4[j][2]);
            h4[j][3] = fmaf(pn, x[j][3], h4[j][3]);
        }
    };

    #pragma unroll
    for (int i = 0; i < NSTEP1; ++i) {
        if (i + 2 < NSTEP1)
            LOADROW(xbuf[(i + 2) % 3], (i + 2) * NTEAM1 + team, (actbits >> (i + 2)) & 1);
        PROCROW(xbuf[i % 3], i * NTEAM1 + team, (actbits >> i) & 1);
    }

    // publish 32 team partials
    #pragma unroll
    for (int j = 0; j < 4; ++j) *(f4*)(&hm[team][l16 * 4 + j * 64]) = h4[j];
    if (l16 == 0) l_s[team] = l_acc;
    __syncthreads();

    // -------- phase 4: partial merge -> ws, raw pn -> out
    {
        const int rg = t >> 8;        // 0..1
        const int d  = t & 255;
        float hsum = 0.0f;
        #pragma unroll
        for (int pp = 0; pp < 16; ++pp) hsum += hm[rg * 16 + pp][d];
        hq[rg][d] = hsum;
    }
    if (t < ROWS2) out[b * Nc + n0 + t] = pn_s[t];   // raw pn (k2 normalizes)
    if (t == 0) {
        float L = 0.0f;
        #pragma unroll
        for (int p = 0; p < NTEAM1; ++p) L += l_s[p];
        ws[WS_L + (size_t)b * SPLIT2 + s] = L;
    }
    __syncthreads();
    if (t < Dc)
        ws[WS_H + ((size_t)b * SPLIT2 + s) * Dc + t] = hq[0][t] + hq[1][t];
}

// ---------------------------------------------------------------- kernel 2
// grid 256, 256 threads: combine 2 partials, normalize alpha, ctx = hbar @ Wv^T.
__global__ __launch_bounds__(256) void k2_merge(
    const float* __restrict__ Wv, const float* __restrict__ ws,
    float* __restrict__ out)
{
    const int b = blockIdx.x;
    const int t = threadIdx.x;
    const int wave = t >> 6, lane = t & 63, g = lane >> 4, l16 = lane & 15;

    __shared__ __align__(16) float hbar[Dc];

    const float L = ws[WS_L + (size_t)b * SPLIT2] + ws[WS_L + (size_t)b * SPLIT2 + 1];
    const float invL = 1.0f / L;

    hbar[t] = (ws[WS_H + ((size_t)b * SPLIT2 + 0) * Dc + t] +
               ws[WS_H + ((size_t)b * SPLIT2 + 1) * Dc + t]) * invL;

    // normalize alpha in place (raw pn written by k1)
    #pragma unroll
    for (int i = 0; i < Nc / 256; ++i) {
        const int idx = b * Nc + i * 256 + t;
        out[idx] = out[idx] * invL;
    }
    __syncthreads();

    float4 hb4[4];
    #pragma unroll
    for (int j = 0; j < 4; ++j) hb4[j] = *(const float4*)(hbar + l16 * 4 + j * 64);
    float* __restrict__ ctx_out = out + (size_t)Bc * Nc + b * Dc;
    #pragma unroll
    for (int step = 0; step < 16; ++step) {
        const int e = step * 16 + wave * 4 + g;
        float acc = 0.0f;
        #pragma unroll
        for (int j = 0; j < 4; ++j) {
            const float4 wv = *(const float4*)(Wv + e * Dc + l16 * 4 + j * 64);
            acc += wv.x * hb4[j].x + wv.y * hb4[j].y + wv.z * hb4[j].z + wv.w * hb4[j].w;
        }
        #pragma unroll
        for (int off = 1; off < 16; off <<= 1) acc += __shfl_xor(acc, off);
        if (l16 == 0) ctx_out[e] = acc;
    }
}

// ---------------------------------------------------------------- fallback
// R3 fused single kernel (validated, ws-free) for small ws_size.
constexpr int NT    = 1024;
constexpr int NTEAM = 64;
constexpr int NSTEP = Nc / NTEAM;

__global__ __launch_bounds__(NT) void fba_fused(
    const float* __restrict__ tokns_k, const float* __restrict__ H_pad,
    const int* __restrict__ mask, const float* __restrict__ Wq,
    const float* __restrict__ Wk, const float* __restrict__ Wv,
    const float* __restrict__ log_scale, float* __restrict__ out)
{
    const int b = blockIdx.x;
    const int t = threadIdx.x;
    const int wave = t >> 6, lane = t & 63, g = lane >> 4, l16 = lane & 15;
    const int team = wave * 4 + g;     // 0..63

    __shared__ float q_s[Rc];
    __shared__ __align__(16) float p_s[Dc];
    __shared__ __align__(16) float hm[NTEAM][Dc];
    __shared__ __align__(16) float hq[4][Dc];
    __shared__ float l_s[NTEAM];
    __shared__ float pn_s[Nc];
    __shared__ __align__(16) float hbar[Dc];
    __shared__ int   mask_s[Nc];

    if (t < Nc) mask_s[t] = mask[b * Nc + t];

    const float inv_scale = 1.0f / fmaxf(__expf(log_scale[0]), 0.1f);

    {
        const int r = team;
        float acc = 0.0f;
        #pragma unroll
        for (int j = 0; j < 4; ++j) {
            const float4 tk = *(const float4*)(tokns_k + b * Dc + l16 * 4 + j * 64);
            const float4 wq = *(const float4*)(Wq + r * Dc + l16 * 4 + j * 64);
            acc += tk.x * wq.x + tk.y * wq.y + tk.z * wq.z + tk.w * wq.w;
        }
        #pragma unroll
        for (int off = 1; off < 16; off <<= 1) acc += __shfl_xor(acc, off);
        if (l16 == 0) q_s[r] = acc;
    }
    __syncthreads();

    {
        const int rg = t >> 8;
        const int d  = t & 255;
        float acc = 0.0f;
        #pragma unroll
        for (int rr = 0; rr < 16; ++rr) {
            const int r = rg * 16 + rr;
            acc += q_s[r] * Wk[r * Dc + d];
        }
        hq[rg][d] = acc;
    }
    __syncthreads();
    if (t < Dc) p_s[t] = (hq[0][t] + hq[1][t]) + (hq[2][t] + hq[3][t]);
    __syncthreads();

    float4 p4[4];
    #pragma unroll
    for (int j = 0; j < 4; ++j) p4[j] = *(const float4*)(p_s + l16 * 4 + j * 64);

    int actbits = 0;
    #pragma unroll
    for (int k = 0; k < NSTEP; ++k)
        actbits |= (mask_s[k * NTEAM + team] != 0) ? (1 << k) : 0;

    const float* __restrict__ Hb = H_pad + (size_t)b * Nc * Dc;
    float  l_acc = 0.0f;
    float4 h4[4];
    #pragma unroll
    for (int j = 0; j < 4; ++j) h4[j] = make_float4(0.f, 0.f, 0.f, 0.f);

    auto LOADROW = [&](f4 (&x)[4], int nr, bool act) {
        if (act) {
            const float* __restrict__ row = Hb + nr * Dc + l16 * 4;
            #pragma unroll
            for (int j = 0; j < 4; ++j)
                x[j] = __builtin_nontemporal_load((const f4*)(row + j * 64));
        }
    };
    auto PROCROW = [&](const f4 (&x)[4], int nr, bool act) {
        if (!act) {
            if (l16 == 0) pn_s[nr] = 0.0f;
            return;
        }
        float s0 = x[0][0] * p4[0].x + x[0][1] * p4[0].y + x[0][2] * p4[0].z + x[0][3] * p4[0].w;
        float s1 = x[1][0] * p4[1].x + x[1][1] * p4[1].y + x[1][2] * p4[1].z + x[1][3] * p4[1].w;
        float s2 = x[2][0] * p4[2].x + x[2][1] * p4[2].y + x[2][2] * p4[2].z + x[2][3] * p4[2].w;
        float s3 = x[3][0] * p4[3].x + x[3][1] * p4[3].y + x[3][2] * p4[3].z + x[3][3] * p4[3].w;
        float sc = (s0 + s1) + (s2 + s3);
        #pragma unroll
        for (int off = 1; off < 16; off <<= 1) sc += __shfl_xor(sc, off);
        sc *= inv_scale;

        const float pn = __expf(sc);
        if (l16 == 0) pn_s[nr] = pn;
        l_acc += pn;
        #pragma unroll
        for (int j = 0; j < 4; ++j) {
            h4[j].x = fmaf(pn, x[j][0], h4[j].x);
            h4[j].y = fmaf(pn, x[j][1], h4[j].y);
            h4[j].z = fmaf(pn, x[j][2], h4[j].z);
            h4[j].w = fmaf(pn, x[j][3], h4[j].w);
        }
    };

    f4 xa[4], xb[4];
    LOADROW(xa, team, (actbits >> 0) & 1);
    #pragma unroll
    for (int it = 0; it < NSTEP / 2; ++it) {
        const int nrA = it * (2 * NTEAM) + team;
        const int nrB = nrA + NTEAM;
        const bool actA = (actbits >> (2 * it)) & 1;
        const bool actB = (actbits >> (2 * it + 1)) & 1;
        LOADROW(xb, nrB, actB);
        PROCROW(xa, nrA, actA);
        if (it + 1 < NSTEP / 2)
            LOADROW(xa, nrA + 2 * NTEAM, (actbits >> (2 * it + 2)) & 1);
        PROCROW(xb, nrB, actB);
    }

    #pragma unroll
    for (int j = 0; j < 4; ++j) *(float4*)(&hm[team][l16 * 4 + j * 64]) = h4[j];
    if (l16 == 0) l_s[team] = l_acc;
    __syncthreads();

    float L = 0.0f;
    #pragma unroll
    for (int p = 0; p < NTEAM; ++p) L += l_s[p];
    const float invL = 1.0f / L;

    {
        const int rg = t >> 8;
        const int d  = t & 255;
        float hsum = 0.0f;
        #pragma unroll
        for (int pp = 0; pp < 16; ++pp) hsum += hm[rg * 16 + pp][d];
        hq[rg][d] = hsum;
    }
    if (t < Nc) out[b * Nc + t] = pn_s[t] * invL;
    __syncthreads();
    if (t < Dc) hbar[t] = ((hq[0][t] + hq[1][t]) + (hq[2][t] + hq[3][t])) * invL;
    __syncthreads();

    float4 hb4[4];
    #pragma unroll
    for (int j = 0; j < 4; ++j) hb4[j] = *(const float4*)(hbar + l16 * 4 + j * 64);
    float* __restrict__ ctx_out = out + (size_t)Bc * Nc + b * Dc;
    #pragma unroll
    for (int step = 0; step < Dc / NTEAM; ++step) {
        const int e = step * NTEAM + team;
        float acc = 0.0f;
        #pragma unroll
        for (int j = 0; j < 4; ++j) {
            const float4 wv = *(const float4*)(Wv + e * Dc + l16 * 4 + j * 64);
            acc += wv.x * hb4[j].x + wv.y * hb4[j].y + wv.z * hb4[j].z + wv.w * hb4[j].w;
        }
        #pragma unroll
        for (int off = 1; off < 16; off <<= 1) acc += __shfl_xor(acc, off);
        if (l16 == 0) ctx_out[e] = acc;
    }
}

extern "C" void kernel_launch(void* const* d_in, const int* in_sizes, int n_in,
                              void* d_out, int out_size, void* d_ws, size_t ws_size,
                              hipStream_t stream) {
    const float* tokns_k   = (const float*)d_in[0];
    const float* H_pad     = (const float*)d_in[1];
    const int*   mask      = (const int*)d_in[2];
    const float* Wq        = (const float*)d_in[3];
    const float* Wk        = (const float*)d_in[4];
    const float* Wv        = (const float*)d_in[5];
    const float* log_scale = (const float*)d_in[6];
    float* out = (float*)d_out;

    if (ws_size >= WS_FLOATS * sizeof(float)) {
        float* ws = (float*)d_ws;
        dim3 grid1(SPLIT2, Bc);
        k1_half<<<grid1, NT1, 0, stream>>>(tokns_k, H_pad, mask, Wq, Wk,
                                           log_scale, ws, out);
        k2_merge<<<Bc, 256, 0, stream>>>(Wv, ws, out);
    } else {
        fba_fused<<<Bc, NT, 0, stream>>>(tokns_k, H_pad, mask, Wq, Wk, Wv,
                                         log_scale, out);
    }
}

// Round 6
// 187.740 us; speedup vs baseline: 1.0529x; 1.0529x over previous
//
#include <hip/hip_runtime.h>

// Problem constants
constexpr int Bc = 256;   // batch
constexpr int Nc = 512;   // nodes
constexpr int Dc = 256;   // dim_graph == dim_desc
constexpr int Rc = 64;    // rank

constexpr int NT    = 1024;         // threads per block (16 waves -> 4 waves/SIMD)
constexpr int NTEAM = 64;           // 16-lane teams per block
constexpr int NSTEP = Nc / NTEAM;   // 8 rows per team

typedef float f4 __attribute__((ext_vector_type(4)));

// ---------------------------------------------------------------- fused kernel
// R3 champion structure (187.4 us) + two de-confounded tweaks from R5:
//   (a) first two H-row loads issued BEFORE phase 2 (HBM latency hides under
//       the p = q@Wk compute),
//   (b) p4 summed directly from the four hq partials (drops p_s staging pass
//       and one __syncthreads).
// One block per batch element b, 1024 threads.
//   1. q = tokns_k[b] @ Wq^T            (64 teams, 1 row each)
//   2. p = q @ Wk                       (4 r-chunks across waves)
//   3. stream H rows: 16-lane teams, mask bitmap, 2-deep pipeline
//      masked rows: NO load, pn exactly 0 (validated R1-R5 semantics)
//   4. tree-reduce 64 team partials, alpha, hbar
//   5. ctx = hbar @ Wv^T
// Workspace is NOT used anywhere.
__global__ __launch_bounds__(NT) void fba_fused(
    const float* __restrict__ tokns_k, const float* __restrict__ H_pad,
    const int* __restrict__ mask, const float* __restrict__ Wq,
    const float* __restrict__ Wk, const float* __restrict__ Wv,
    const float* __restrict__ log_scale, float* __restrict__ out)
{
    const int b = blockIdx.x;
    const int t = threadIdx.x;
    const int wave = t >> 6, lane = t & 63, g = lane >> 4, l16 = lane & 15;
    const int team = wave * 4 + g;     // 0..63

    __shared__ float q_s[Rc];
    __shared__ __align__(16) float hm[NTEAM][Dc];   // 64 KB team partials
    __shared__ __align__(16) float hq[4][Dc];       // 4 KB p-partials / merge temp
    __shared__ float l_s[NTEAM];
    __shared__ float pn_s[Nc];                      // exp(score) (LDS only)
    __shared__ __align__(16) float hbar[Dc];
    __shared__ int   mask_s[Nc];

    if (t < Nc) mask_s[t] = mask[b * Nc + t];

    const float inv_scale = 1.0f / fmaxf(__expf(log_scale[0]), 0.1f);

    // -------- phase 1: q[r] = tokns_k[b] . Wq[r]   (team r handles row r)
    {
        const int r = team;
        float acc = 0.0f;
        #pragma unroll
        for (int j = 0; j < 4; ++j) {
            const float4 tk = *(const float4*)(tokns_k + b * Dc + l16 * 4 + j * 64);
            const float4 wq = *(const float4*)(Wq + r * Dc + l16 * 4 + j * 64);
            acc += tk.x * wq.x + tk.y * wq.y + tk.z * wq.z + tk.w * wq.w;
        }
        #pragma unroll
        for (int off = 1; off < 16; off <<= 1) acc += __shfl_xor(acc, off);
        if (l16 == 0) q_s[r] = acc;
    }
    __syncthreads();                    // q_s and mask_s ready

    // hoist this team's 8 mask bits into a register bitmap
    int actbits = 0;
    #pragma unroll
    for (int k = 0; k < NSTEP; ++k)
        actbits |= (mask_s[k * NTEAM + team] != 0) ? (1 << k) : 0;

    const float* __restrict__ Hb = H_pad + (size_t)b * Nc * Dc;

    auto LOADROW = [&](f4 (&x)[4], int nr, bool act) {
        if (act) {
            const float* __restrict__ row = Hb + nr * Dc + l16 * 4;
            #pragma unroll
            for (int j = 0; j < 4; ++j)
                x[j] = __builtin_nontemporal_load((const f4*)(row + j * 64));
        }
    };

    // (a) issue first two row-loads NOW — latency hides under phase 2
    f4 xa[4], xb[4];
    LOADROW(xa, 0 * NTEAM + team, (actbits >> 0) & 1);
    LOADROW(xb, 1 * NTEAM + team, (actbits >> 1) & 1);

    // -------- phase 2: p[d] = sum_r q[r] * Wk[r][d]  (4 r-chunks across waves)
    {
        const int rg = t >> 8;        // 0..3  (chunk of 16 r's)
        const int d  = t & 255;
        float acc = 0.0f;
        #pragma unroll
        for (int rr = 0; rr < 16; ++rr) {
            const int r = rg * 16 + rr;
            acc += q_s[r] * Wk[r * Dc + d];
        }
        hq[rg][d] = acc;
    }
    __syncthreads();

    // (b) per-lane p fragment straight from the four partials (no p_s pass)
    f4 p4[4];
    #pragma unroll
    for (int j = 0; j < 4; ++j)
        p4[j] = (*(const f4*)(&hq[0][l16 * 4 + j * 64]) +
                 *(const f4*)(&hq[1][l16 * 4 + j * 64])) +
                (*(const f4*)(&hq[2][l16 * 4 + j * 64]) +
                 *(const f4*)(&hq[3][l16 * 4 + j * 64]));

    // -------- phase 3: stream H rows, 2-deep statically-indexed pipeline
    float l_acc = 0.0f;
    f4 h4[4];
    #pragma unroll
    for (int j = 0; j < 4; ++j) h4[j] = (f4){0.f, 0.f, 0.f, 0.f};

    auto PROCROW = [&](const f4 (&x)[4], int nr, bool act) {
        if (!act) {
            // masked out: alpha exactly 0, no load done
            if (l16 == 0) pn_s[nr] = 0.0f;
            return;
        }
        float s0 = x[0][0] * p4[0][0] + x[0][1] * p4[0][1] + x[0][2] * p4[0][2] + x[0][3] * p4[0][3];
        float s1 = x[1][0] * p4[1][0] + x[1][1] * p4[1][1] + x[1][2] * p4[1][2] + x[1][3] * p4[1][3];
        float s2 = x[2][0] * p4[2][0] + x[2][1] * p4[2][1] + x[2][2] * p4[2][2] + x[2][3] * p4[2][3];
        float s3 = x[3][0] * p4[3][0] + x[3][1] * p4[3][1] + x[3][2] * p4[3][2] + x[3][3] * p4[3][3];
        float sc = (s0 + s1) + (s2 + s3);
        #pragma unroll
        for (int off = 1; off < 16; off <<= 1) sc += __shfl_xor(sc, off);
        sc *= inv_scale;

        const float pn = __expf(sc);     // |scores| << 88: no overflow (validated R2-R6)
        if (l16 == 0) pn_s[nr] = pn;
        l_acc += pn;
        #pragma unroll
        for (int j = 0; j < 4; ++j) {
            h4[j][0] = fmaf(pn, x[j][0], h4[j][0]);
            h4[j][1] = fmaf(pn, x[j][1], h4[j][1]);
            h4[j][2] = fmaf(pn, x[j][2], h4[j][2]);
            h4[j][3] = fmaf(pn, x[j][3], h4[j][3]);
        }
    };

    #pragma unroll
    for (int it = 0; it < NSTEP / 2; ++it) {
        const int nrA = it * (2 * NTEAM) + team;
        const int nrB = nrA + NTEAM;
        const bool actA = (actbits >> (2 * it)) & 1;
        const bool actB = (actbits >> (2 * it + 1)) & 1;
        PROCROW(xa, nrA, actA);
        if (it + 1 < NSTEP / 2)
            LOADROW(xa, nrA + 2 * NTEAM, (actbits >> (2 * it + 2)) & 1);
        PROCROW(xb, nrB, actB);
        if (it + 1 < NSTEP / 2)
            LOADROW(xb, nrB + 2 * NTEAM, (actbits >> (2 * it + 3)) & 1);
    }

    // publish 64 team partials
    #pragma unroll
    for (int j = 0; j < 4; ++j) *(f4*)(&hm[team][l16 * 4 + j * 64]) = h4[j];
    if (l16 == 0) l_s[team] = l_acc;
    __syncthreads();

    // -------- phase 4: merge partials (tree), alpha, hbar
    float L = 0.0f;
    #pragma unroll
    for (int p = 0; p < NTEAM; ++p) L += l_s[p];   // broadcast reads, conflict-free
    const float invL = 1.0f / L;

    {
        const int rg = t >> 8;        // 0..3
        const int d  = t & 255;
        float hsum = 0.0f;
        #pragma unroll
        for (int pp = 0; pp < 16; ++pp) hsum += hm[rg * 16 + pp][d];
        hq[rg][d] = hsum;
    }
    if (t < Nc) out[b * Nc + t] = pn_s[t] * invL;   // alpha
    __syncthreads();
    if (t < Dc) hbar[t] = ((hq[0][t] + hq[1][t]) + (hq[2][t] + hq[3][t])) * invL;
    __syncthreads();

    // -------- phase 5: ctx = hbar @ Wv^T
    f4 hb4[4];
    #pragma unroll
    for (int j = 0; j < 4; ++j) hb4[j] = *(const f4*)(hbar + l16 * 4 + j * 64);
    float* __restrict__ ctx_out = out + (size_t)Bc * Nc + b * Dc;
    #pragma unroll
    for (int step = 0; step < Dc / NTEAM; ++step) {
        const int e = step * NTEAM + team;
        float acc = 0.0f;
        #pragma unroll
        for (int j = 0; j < 4; ++j) {
            const f4 wv = *(const f4*)(Wv + e * Dc + l16 * 4 + j * 64);
            acc += wv[0] * hb4[j][0] + wv[1] * hb4[j][1] + wv[2] * hb4[j][2] + wv[3] * hb4[j][3];
        }
        #pragma unroll
        for (int off = 1; off < 16; off <<= 1) acc += __shfl_xor(acc, off);
        if (l16 == 0) ctx_out[e] = acc;
    }
}

extern "C" void kernel_launch(void* const* d_in, const int* in_sizes, int n_in,
                              void* d_out, int out_size, void* d_ws, size_t ws_size,
                              hipStream_t stream) {
    const float* tokns_k   = (const float*)d_in[0];
    const float* H_pad     = (const float*)d_in[1];
    const int*   mask      = (const int*)d_in[2];
    const float* Wq        = (const float*)d_in[3];
    const float* Wk        = (const float*)d_in[4];
    const float* Wv        = (const float*)d_in[5];
    const float* log_scale = (const float*)d_in[6];
    float* out = (float*)d_out;
    (void)d_ws; (void)ws_size;   // workspace intentionally untouched

    fba_fused<<<Bc, NT, 0, stream>>>(tokns_k, H_pad, mask, Wq, Wk, Wv,
                                     log_scale, out);
}